// Round 4
// baseline (392.636 us; speedup 1.0000x reference)
//
#include <hip/hip_runtime.h>
#include <math.h>

// Problem constants (B=2, H=8, S=2048, D=64)
#define BH_    16          // B*H
#define S_     2048
#define D_     64
#define QT     16          // queries per block == MFMA M
#define BLOCK  1024        // 16 waves
#define NW     16
#define KTW    8           // 16x16 C-tiles per wave: 8*16 = 128 keys/wave
#define CAP    320         // candidate cap AFTER 4 Newton pre-iters (n~40-100
                           // even for 1e-8-tail low-|q| rows; R3's m-1 threshold
                           // overflowed CAP=384 on ~hundreds of rows -> FAIL)
#define ITPRE  4           // block-level Newton iterations before compaction
#define WMAXIT 16
#define KELEMS (BH_ * S_ * D_)   // 2,097,152 K elements

typedef __attribute__((ext_vector_type(8))) short bf16x8;   // 8 bf16 = 4 VGPR
typedef __attribute__((ext_vector_type(4))) float f32x4;

// Exact hi/lo bf16 truncation split of 8 consecutive floats.
// x = hi + lo + eps, |eps| <= 2^-15 |x|; products use hh + hl + lh (drop ll).
__device__ __forceinline__ void split8(const float4 f0, const float4 f1,
                                       bf16x8& hi, bf16x8& lo) {
  union { bf16x8 v; unsigned int u[4]; } H, L;
  const float ff[8] = {f0.x, f0.y, f0.z, f0.w, f1.x, f1.y, f1.z, f1.w};
#pragma unroll
  for (int p = 0; p < 4; ++p) {
    unsigned int b0 = __float_as_uint(ff[2 * p]);
    unsigned int b1 = __float_as_uint(ff[2 * p + 1]);
    unsigned int h0 = b0 & 0xFFFF0000u;
    unsigned int h1 = b1 & 0xFFFF0000u;
    H.u[p] = (h0 >> 16) | h1;                       // lo short = elem 2p
    float l0 = ff[2 * p]     - __uint_as_float(h0); // exact in fp32
    float l1 = ff[2 * p + 1] - __uint_as_float(h1);
    L.u[p] = (__float_as_uint(l0) >> 16) | (__float_as_uint(l1) & 0xFFFF0000u);
  }
  hi = H.v; lo = L.v;
}

// Prepass: K fp32 -> (Khi, Klo) bf16, same [bh][key][d] element order.
__global__ __launch_bounds__(256)
void ksplit_kernel(const float* __restrict__ k,
                   unsigned short* __restrict__ khi,
                   unsigned short* __restrict__ klo) {
  const int i = (blockIdx.x * 256 + threadIdx.x) * 4;
  float4 x = *(const float4*)(k + i);
  ushort4 h, l;
  {
    unsigned int b;
    b = __float_as_uint(x.x); h.x = (unsigned short)(b >> 16);
    l.x = (unsigned short)(__float_as_uint(x.x - __uint_as_float(b & 0xFFFF0000u)) >> 16);
    b = __float_as_uint(x.y); h.y = (unsigned short)(b >> 16);
    l.y = (unsigned short)(__float_as_uint(x.y - __uint_as_float(b & 0xFFFF0000u)) >> 16);
    b = __float_as_uint(x.z); h.z = (unsigned short)(b >> 16);
    l.z = (unsigned short)(__float_as_uint(x.z - __uint_as_float(b & 0xFFFF0000u)) >> 16);
    b = __float_as_uint(x.w); h.w = (unsigned short)(b >> 16);
    l.w = (unsigned short)(__float_as_uint(x.w - __uint_as_float(b & 0xFFFF0000u)) >> 16);
  }
  *(ushort4*)(khi + i) = h;
  *(ushort4*)(klo + i) = l;
}

template <bool PRE>
__global__ __launch_bounds__(BLOCK, 4)   // cap VGPR at 128
void entmax_attn_kernel(const float* __restrict__ q,
                        const float* __restrict__ k,
                        const unsigned short* __restrict__ khi,
                        const unsigned short* __restrict__ klo,
                        const float* __restrict__ v,
                        float* __restrict__ out) {
  __shared__ float redM[NW][QT];          // rowmax partials
  __shared__ float redS1[2][NW][QT];      // double-buffered Newton partials
  __shared__ float redS2[2][NW][QT];      // (2 bufs -> 1 barrier per iter, no WAR)
  __shared__ unsigned int cnt[QT];
  __shared__ int   lidx[QT][CAP];         // candidates: key index
  __shared__ float lval[QT][CAP];         // candidates: x, later p

  const int t    = threadIdx.x;
  const int wid  = t >> 6;             // 0..15
  const int lane = t & 63;
  const int g    = lane >> 4;          // lane group 0..3
  const int col  = lane & 15;          // MFMA col index (key)
  const int rm   = lane & 15;          // row this lane serves in reductions

  const int bh = blockIdx.x >> 7;      // 16 heads
  const int qt = blockIdx.x & 127;     // 128 q-tiles of 16
  const float* qp = q + ((size_t)bh * S_ + (size_t)qt * QT) * D_;
  const float* kp = k + (size_t)bh * S_ * D_;
  const float* vp = v + (size_t)bh * S_ * D_;
  float* op = out + ((size_t)bh * S_ + (size_t)qt * QT) * D_;

  if (t < QT) cnt[t] = 0;

  // ---- Q fragments (identical in all waves): A row m = col, d = ks*32+g*8+i.
  // Fold scale (1/8) and entmax /2 => *1/16 (power of 2: exact prescale).
  bf16x8 qh[2], ql[2];
#pragma unroll
  for (int ks = 0; ks < 2; ++ks) {
    const float* src = qp + col * D_ + ks * 32 + g * 8;
    float4 f0 = *(const float4*)src;
    float4 f1 = *(const float4*)(src + 4);
    f0.x *= 0.0625f; f0.y *= 0.0625f; f0.z *= 0.0625f; f0.w *= 0.0625f;
    f1.x *= 0.0625f; f1.y *= 0.0625f; f1.z *= 0.0625f; f1.w *= 0.0625f;
    split8(f0, f1, qh[ks], ql[ks]);
  }

  // ---- QK^T: wave wid owns keys [wid*128, wid*128+128), 8 C-tiles.
  // acc[kt][j] = x[row = g*4+j][key = wid*128 + kt*16 + col]
  // fp32-ish accuracy: qh*kh + qh*kl + ql*kh (drop ll, ~2^-15 rel).
  f32x4 acc[KTW];
  const f32x4 zero4 = {0.f, 0.f, 0.f, 0.f};
#pragma unroll
  for (int kt = 0; kt < KTW; ++kt) {
    acc[kt] = zero4;
    const size_t rowoff = (size_t)(wid * 128 + kt * 16 + col) * D_;
#pragma unroll
    for (int ks = 0; ks < 2; ++ks) {
      bf16x8 kh, kl;
      if (PRE) {
        const size_t eoff = (size_t)bh * S_ * D_ + rowoff + ks * 32 + g * 8;
        kh = *(const bf16x8*)(khi + eoff);
        kl = *(const bf16x8*)(klo + eoff);
      } else {
        const float* src = kp + rowoff + ks * 32 + g * 8;
        split8(*(const float4*)src, *(const float4*)(src + 4), kh, kl);
      }
      acc[kt] = __builtin_amdgcn_mfma_f32_16x16x32_bf16(qh[ks], kh, acc[kt], 0, 0, 0);
      acc[kt] = __builtin_amdgcn_mfma_f32_16x16x32_bf16(qh[ks], kl, acc[kt], 0, 0, 0);
      acc[kt] = __builtin_amdgcn_mfma_f32_16x16x32_bf16(ql[ks], kh, acc[kt], 0, 0, 0);
    }
  }

  // ---- row max: wave butterfly over 16 cols, publish, lane-parallel combine.
  {
    float m4l[4];
#pragma unroll
    for (int j = 0; j < 4; ++j) {
      float mm = acc[0][j];
#pragma unroll
      for (int kt = 1; kt < KTW; ++kt) mm = fmaxf(mm, acc[kt][j]);
      m4l[j] = mm;
    }
#pragma unroll
    for (int off = 1; off < 16; off <<= 1) {
#pragma unroll
      for (int j = 0; j < 4; ++j) m4l[j] = fmaxf(m4l[j], __shfl_xor(m4l[j], off, 64));
    }
    if (col == 0) {
#pragma unroll
      for (int j = 0; j < 4; ++j) redM[wid][g * 4 + j] = m4l[j];
    }
  }
  __syncthreads();                                    // barrier 1

  // Mrow: max of row rm across waves (valid in every lane for row lane&15).
  float Mrow = redM[0][rm];
#pragma unroll
  for (int w = 1; w < NW; ++w) Mrow = fmaxf(Mrow, redM[w][rm]);

  // tauR: tau for row rm (valid where (lane&16)==0); tau[j]: rows g*4+j.
  float tauR = Mrow - 1.0f;   // provable lower bound: sum p = 1, p<=1 each
  float tau[4];
#pragma unroll
  for (int j = 0; j < 4; ++j) tau[j] = __shfl(Mrow, g * 4 + j) - 1.0f;

  // ---- ITPRE block-level Newton iterations (from below -> tau <= tau*).
  // One barrier each: butterfly partials -> LDS (dbuf) -> barrier ->
  // lane-parallel totals (lanes lr<16: S1[row lr], lr>=16: S2[row lr-16]).
  for (int it = 0; it < ITPRE; ++it) {
    const int b = it & 1;
    float s1[4] = {0, 0, 0, 0}, s2[4] = {0, 0, 0, 0};
#pragma unroll
    for (int kt = 0; kt < KTW; ++kt) {
#pragma unroll
      for (int j = 0; j < 4; ++j) {
        float u = fmaxf(acc[kt][j] - tau[j], 0.f);
        s1[j] += u; s2[j] = fmaf(u, u, s2[j]);
      }
    }
#pragma unroll
    for (int off = 1; off < 16; off <<= 1) {
#pragma unroll
      for (int j = 0; j < 4; ++j) {
        s1[j] += __shfl_xor(s1[j], off, 64);
        s2[j] += __shfl_xor(s2[j], off, 64);
      }
    }
    if (col == 0) {
#pragma unroll
      for (int j = 0; j < 4; ++j) {
        redS1[b][wid][g * 4 + j] = s1[j];
        redS2[b][wid][g * 4 + j] = s2[j];
      }
    }
    __syncthreads();                                  // barriers 2..5
    const int lr = lane & 31;
    const float* pS = (lr < 16) ? &redS1[b][0][lr] : &redS2[b][0][lr - 16];
    float T = 0.f;
#pragma unroll
    for (int w = 0; w < NW; ++w) T += pS[w * QT];
    float other = __shfl_xor(T, 16, 64);              // partner's S2 (or S1)
    float step_r = (other - 1.0f) / (2.0f * T);       // valid where lr<16
    if ((lane & 16) == 0) tauR += step_r;
#pragma unroll
    for (int j = 0; j < 4; ++j) tau[j] += __shfl(step_r, g * 4 + j);
  }

  // ---- candidate compaction with threshold tau_pre (<= tau*, so the list
  // contains the full support; restricted f == true f on [tau_pre, inf)).
#pragma unroll
  for (int kt = 0; kt < KTW; ++kt) {
#pragma unroll
    for (int j = 0; j < 4; ++j) {
      float x = acc[kt][j];
      if (x > tau[j]) {
        const int row = g * 4 + j;
        unsigned int s = atomicAdd(&cnt[row], 1u);
        if (s < CAP) {
          lidx[row][s] = wid * 128 + kt * 16 + col;
          lval[row][s] = x;
        }
      }
    }
  }
  __syncthreads();                                    // barrier 6

  // ---- wave-local Newton: wave w solves row w, zero barriers in the loop.
  const int row = wid;
  int n = (int)cnt[row]; if (n > CAP) n = CAP;
  float xv[5];                                        // 5*64 = CAP
#pragma unroll
  for (int r = 0; r < 5; ++r) {
    const int i = lane + 64 * r;
    xv[r] = (i < n) ? lval[row][i] : -1e30f;          // invalid -> u = 0
  }
  float tw = __shfl(tauR, wid);                       // tau_pre for this row
  for (int it = 0; it < WMAXIT; ++it) {
    float s1 = 0.f, s2 = 0.f;
#pragma unroll
    for (int r = 0; r < 5; ++r) {
      float u = fmaxf(xv[r] - tw, 0.f);
      s1 += u; s2 = fmaf(u, u, s2);
    }
#pragma unroll
    for (int off = 1; off < 64; off <<= 1) {
      s1 += __shfl_xor(s1, off, 64);
      s2 += __shfl_xor(s2, off, 64);
    }
    float step = (s2 - 1.0f) / (2.0f * s1);           // s1 >= 1 below root
    tw += step;
    if (step < 1e-7f) break;                          // lane-uniform
  }
  // p = (x - tau)_+^2 written back; barrier publishes for broadcast PV reads.
#pragma unroll
  for (int r = 0; r < 5; ++r) {
    const int i = lane + 64 * r;
    if (i < n) {
      float u = fmaxf(xv[r] - tw, 0.f);
      lval[row][i] = u * u;
    }
  }
  __syncthreads();                                    // barrier 7

  // ---- PV: wave w -> out row w; lane = d. p broadcast from LDS; the
  // `p > 0` skip is wave-uniform and drops ~60-80% of candidate V loads.
  {
    float s = 0.f;
    for (int i = 0; i < n; ++i) {
      float pv = lval[row][i];
      if (pv > 0.f)
        s = fmaf(pv, vp[(size_t)lidx[row][i] * D_ + lane], s);
    }
    op[row * D_ + lane] = s;
  }
}

extern "C" void kernel_launch(void* const* d_in, const int* in_sizes, int n_in,
                              void* d_out, int out_size, void* d_ws, size_t ws_size,
                              hipStream_t stream) {
  const float* q = (const float*)d_in[0];
  const float* k = (const float*)d_in[1];
  const float* v = (const float*)d_in[2];
  float* out = (float*)d_out;
  dim3 grid(BH_ * (S_ / QT));   // 16 * 128 = 2048 blocks
  const size_t need = (size_t)KELEMS * 2 * sizeof(unsigned short);  // 8.4 MB
  if (d_ws != nullptr && ws_size >= need) {
    unsigned short* khi = (unsigned short*)d_ws;
    unsigned short* klo = khi + KELEMS;
    ksplit_kernel<<<dim3(KELEMS / (256 * 4)), dim3(256), 0, stream>>>(k, khi, klo);
    entmax_attn_kernel<true><<<grid, dim3(BLOCK), 0, stream>>>(q, k, khi, klo, v, out);
  } else {
    entmax_attn_kernel<false><<<grid, dim3(BLOCK), 0, stream>>>(q, k, nullptr, nullptr, v, out);
  }
}

// Round 5
// 269.971 us; speedup vs baseline: 1.4544x; 1.4544x over previous
//
#include <hip/hip_runtime.h>
#include <math.h>

// Problem constants (B=2, H=8, S=2048, D=64)
#define BH_    16          // B*H
#define S_     2048
#define D_     64
#define QT     32          // queries per block (2 MFMA A-frags per wave)
#define BLOCK  1024        // 16 waves
#define NW     16
#define KTW    8           // 16x16 C-tiles per wave: 8*16 = 128 keys/wave
#define CAP    256         // cap after ITPRE pre-iters; worst-row n5 ~<=100
#define ITPRE  5           // block-level Newton iterations before compaction
#define WMAXIT 16
#define KELEMS (BH_ * S_ * D_)   // 2,097,152 K elements

typedef __attribute__((ext_vector_type(8))) short bf16x8;   // 8 bf16 = 4 VGPR
typedef __attribute__((ext_vector_type(4))) float f32x4;

// Exact hi/lo bf16 truncation split of 8 consecutive floats.
// x = hi + lo + eps, |eps| <= 2^-15 |x|; products use hh + hl + lh (drop ll).
__device__ __forceinline__ void split8(const float4 f0, const float4 f1,
                                       bf16x8& hi, bf16x8& lo) {
  union { bf16x8 v; unsigned int u[4]; } H, L;
  const float ff[8] = {f0.x, f0.y, f0.z, f0.w, f1.x, f1.y, f1.z, f1.w};
#pragma unroll
  for (int p = 0; p < 4; ++p) {
    unsigned int b0 = __float_as_uint(ff[2 * p]);
    unsigned int b1 = __float_as_uint(ff[2 * p + 1]);
    unsigned int h0 = b0 & 0xFFFF0000u;
    unsigned int h1 = b1 & 0xFFFF0000u;
    H.u[p] = (h0 >> 16) | h1;                       // lo short = elem 2p
    float l0 = ff[2 * p]     - __uint_as_float(h0); // exact in fp32
    float l1 = ff[2 * p + 1] - __uint_as_float(h1);
    L.u[p] = (__float_as_uint(l0) >> 16) | (__float_as_uint(l1) & 0xFFFF0000u);
  }
  hi = H.v; lo = L.v;
}

// Prepass: K fp32 -> (Khi, Klo) bf16, same [bh][key][d] element order.
__global__ __launch_bounds__(256)
void ksplit_kernel(const float* __restrict__ k,
                   unsigned short* __restrict__ khi,
                   unsigned short* __restrict__ klo) {
  const int i = (blockIdx.x * 256 + threadIdx.x) * 4;
  float4 x = *(const float4*)(k + i);
  ushort4 h, l;
  {
    unsigned int b;
    b = __float_as_uint(x.x); h.x = (unsigned short)(b >> 16);
    l.x = (unsigned short)(__float_as_uint(x.x - __uint_as_float(b & 0xFFFF0000u)) >> 16);
    b = __float_as_uint(x.y); h.y = (unsigned short)(b >> 16);
    l.y = (unsigned short)(__float_as_uint(x.y - __uint_as_float(b & 0xFFFF0000u)) >> 16);
    b = __float_as_uint(x.z); h.z = (unsigned short)(b >> 16);
    l.z = (unsigned short)(__float_as_uint(x.z - __uint_as_float(b & 0xFFFF0000u)) >> 16);
    b = __float_as_uint(x.w); h.w = (unsigned short)(b >> 16);
    l.w = (unsigned short)(__float_as_uint(x.w - __uint_as_float(b & 0xFFFF0000u)) >> 16);
  }
  *(ushort4*)(khi + i) = h;
  *(ushort4*)(klo + i) = l;
}

template <bool PRE>
__global__ __launch_bounds__(BLOCK, 4)   // VGPR cap 128
void entmax_attn_kernel(const float* __restrict__ q,
                        const float* __restrict__ k,
                        const unsigned short* __restrict__ khi,
                        const unsigned short* __restrict__ klo,
                        const float* __restrict__ v,
                        float* __restrict__ out) {
  __shared__ float redM[NW][QT];          // rowmax partials
  __shared__ float redS1[2][NW][QT];      // double-buffered Newton partials
  __shared__ float redS2[2][NW][QT];      // (1 barrier/iter, no WAR hazard)
  __shared__ unsigned int cnt[QT];
  __shared__ int   lidx[QT][CAP];         // candidates: key index
  __shared__ float lval[QT][CAP];         // candidates: x, later p
  // total LDS ~74KB -> 2 blocks/CU (148KB < 160KB), 32 waves/CU.

  const int t    = threadIdx.x;
  const int wid  = t >> 6;             // 0..15
  const int lane = t & 63;
  const int g    = lane >> 4;          // lane group 0..3
  const int col  = lane & 15;          // MFMA col (key) / A-row index
  const int rowL = lane & 31;          // row this lane serves in reductions

  // XCD-locality decode: bh = blk & 15 -> blk % 8 == bh % 8, so all 64
  // blocks of a head land on one XCD (round-robin dispatch heuristic);
  // per-XCD working set = 2 heads ~ 4MB ~ L2. Correctness-independent.
  const int blk = blockIdx.x;
  const int bh  = blk & 15;
  const int qt  = blk >> 4;            // 0..63
  const float* qp = q + ((size_t)bh * S_ + (size_t)qt * QT) * D_;
  const float* kp = k + (size_t)bh * S_ * D_;
  const float* vp = v + (size_t)bh * S_ * D_;
  float* op = out + ((size_t)bh * S_ + (size_t)qt * QT) * D_;

  if (t < QT) cnt[t] = 0;

  // ---- Q fragments: A-frag f covers rows f*16..f*16+15 (row = col lane idx).
  // Fold scale (1/8) and entmax /2 => *1/16 (power of 2: exact prescale).
  bf16x8 qh[2][2], ql[2][2];
#pragma unroll
  for (int f = 0; f < 2; ++f) {
#pragma unroll
    for (int ks = 0; ks < 2; ++ks) {
      const float* src = qp + (f * 16 + col) * D_ + ks * 32 + g * 8;
      float4 f0 = *(const float4*)src;
      float4 f1 = *(const float4*)(src + 4);
      f0.x *= 0.0625f; f0.y *= 0.0625f; f0.z *= 0.0625f; f0.w *= 0.0625f;
      f1.x *= 0.0625f; f1.y *= 0.0625f; f1.z *= 0.0625f; f1.w *= 0.0625f;
      split8(f0, f1, qh[f][ks], ql[f][ks]);
    }
  }

  // ---- QK^T: wave wid owns keys [wid*128, wid*128+128).
  // acc[f][kt][j] = x[row = f*16 + g*4 + j][key = wid*128 + kt*16 + col]
  // fp32-ish accuracy: qh*kh + qh*kl + ql*kh (drop ll, ~2^-15 rel).
  // One K-load pair now feeds 6 MFMAs (2 A-frags) -> half the per-query
  // load-latency exposure vs QT=16.
  f32x4 acc[2][KTW];
#pragma unroll
  for (int f = 0; f < 2; ++f)
#pragma unroll
    for (int kt = 0; kt < KTW; ++kt) acc[f][kt] = (f32x4){0.f, 0.f, 0.f, 0.f};
#pragma unroll
  for (int kt = 0; kt < KTW; ++kt) {
    const size_t rowoff = (size_t)(wid * 128 + kt * 16 + col) * D_;
#pragma unroll
    for (int ks = 0; ks < 2; ++ks) {
      bf16x8 kh, kl;
      if (PRE) {
        const size_t eoff = (size_t)bh * S_ * D_ + rowoff + ks * 32 + g * 8;
        kh = *(const bf16x8*)(khi + eoff);
        kl = *(const bf16x8*)(klo + eoff);
      } else {
        const float* src = kp + rowoff + ks * 32 + g * 8;
        split8(*(const float4*)src, *(const float4*)(src + 4), kh, kl);
      }
#pragma unroll
      for (int f = 0; f < 2; ++f) {
        acc[f][kt] = __builtin_amdgcn_mfma_f32_16x16x32_bf16(qh[f][ks], kh, acc[f][kt], 0, 0, 0);
        acc[f][kt] = __builtin_amdgcn_mfma_f32_16x16x32_bf16(qh[f][ks], kl, acc[f][kt], 0, 0, 0);
        acc[f][kt] = __builtin_amdgcn_mfma_f32_16x16x32_bf16(ql[f][ks], kh, acc[f][kt], 0, 0, 0);
      }
    }
  }

  // ---- row max: butterfly over the 16 cols (lanes g*16..g*16+15 hold row
  // f*16+g*4+j), publish per wave, then cross-wave combine per lane's row.
  {
    float m4[2][4];
#pragma unroll
    for (int f = 0; f < 2; ++f)
#pragma unroll
      for (int j = 0; j < 4; ++j) {
        float mm = acc[f][0][j];
#pragma unroll
        for (int kt = 1; kt < KTW; ++kt) mm = fmaxf(mm, acc[f][kt][j]);
        m4[f][j] = mm;
      }
#pragma unroll
    for (int off = 1; off < 16; off <<= 1)
#pragma unroll
      for (int f = 0; f < 2; ++f)
#pragma unroll
        for (int j = 0; j < 4; ++j)
          m4[f][j] = fmaxf(m4[f][j], __shfl_xor(m4[f][j], off, 64));
    if (col == 0) {
#pragma unroll
      for (int f = 0; f < 2; ++f)
#pragma unroll
        for (int j = 0; j < 4; ++j) redM[wid][f * 16 + g * 4 + j] = m4[f][j];
    }
  }
  __syncthreads();                                    // barrier 1

  // tauRow: tau for row rowL (same value in lanes l and l+32).
  float tauRow;
  {
    float mm = redM[0][rowL];
#pragma unroll
    for (int w = 1; w < NW; ++w) mm = fmaxf(mm, redM[w][rowL]);
    tauRow = mm - 1.0f;    // provable lower bound: sum p = 1, each p <= 1
  }
  float tau[2][4];
#pragma unroll
  for (int f = 0; f < 2; ++f)
#pragma unroll
    for (int j = 0; j < 4; ++j) tau[f][j] = __shfl(tauRow, f * 16 + g * 4 + j);

  // ---- ITPRE block-level Newton iterations (from below -> tau <= tau*).
  // One barrier each: butterfly partials -> LDS (dbuf) -> barrier ->
  // lane-parallel totals (lane<32: S1[rowL]; lane>=32: S2[rowL]).
  for (int it = 0; it < ITPRE; ++it) {
    const int b = it & 1;
    float s1[2][4] = {{0,0,0,0},{0,0,0,0}}, s2[2][4] = {{0,0,0,0},{0,0,0,0}};
#pragma unroll
    for (int kt = 0; kt < KTW; ++kt)
#pragma unroll
      for (int f = 0; f < 2; ++f)
#pragma unroll
        for (int j = 0; j < 4; ++j) {
          float u = fmaxf(acc[f][kt][j] - tau[f][j], 0.f);
          s1[f][j] += u; s2[f][j] = fmaf(u, u, s2[f][j]);
        }
#pragma unroll
    for (int off = 1; off < 16; off <<= 1)
#pragma unroll
      for (int f = 0; f < 2; ++f)
#pragma unroll
        for (int j = 0; j < 4; ++j) {
          s1[f][j] += __shfl_xor(s1[f][j], off, 64);
          s2[f][j] += __shfl_xor(s2[f][j], off, 64);
        }
    if (col == 0) {
#pragma unroll
      for (int f = 0; f < 2; ++f)
#pragma unroll
        for (int j = 0; j < 4; ++j) {
          redS1[b][wid][f * 16 + g * 4 + j] = s1[f][j];
          redS2[b][wid][f * 16 + g * 4 + j] = s2[f][j];
        }
    }
    __syncthreads();                                  // barriers 2..6
    const float* pS = (lane < 32) ? &redS1[b][0][rowL] : &redS2[b][0][rowL];
    float T = 0.f;
#pragma unroll
    for (int w = 0; w < NW; ++w) T += pS[w * QT];
    float other = __shfl_xor(T, 32, 64);              // partner's S2 (or S1)
    float step_r = (other - 1.0f) / (2.0f * T);       // valid lanes<32; T=S1>=1
    if (lane < 32) tauRow += step_r;
#pragma unroll
    for (int f = 0; f < 2; ++f)
#pragma unroll
      for (int j = 0; j < 4; ++j)
        tau[f][j] += __shfl(step_r, f * 16 + g * 4 + j);
  }

  // ---- candidate compaction with threshold tau_pre (<= tau*: Newton from
  // below never overshoots, so the list contains the full support).
#pragma unroll
  for (int kt = 0; kt < KTW; ++kt)
#pragma unroll
    for (int f = 0; f < 2; ++f)
#pragma unroll
      for (int j = 0; j < 4; ++j) {
        float x = acc[f][kt][j];
        if (x > tau[f][j]) {
          const int row = f * 16 + g * 4 + j;
          unsigned int s = atomicAdd(&cnt[row], 1u);
          if (s < CAP) {
            lidx[row][s] = wid * 128 + kt * 16 + col;
            lval[row][s] = x;
          }
        }
      }
  __syncthreads();                                    // barrier 7 (last)

  // ---- wave-local Newton + PV: wave w owns rows {2w, 2w+1}; no further
  // barriers (each row's list is read/written only by its owning wave).
  for (int rr = 0; rr < 2; ++rr) {
    const int row = wid * 2 + rr;
    int n = (int)cnt[row]; if (n > CAP) n = CAP;
    float xv[4];                                      // 4*64 = CAP
#pragma unroll
    for (int r = 0; r < 4; ++r) {
      const int i = lane + 64 * r;
      xv[r] = (i < n) ? lval[row][i] : -1e30f;        // invalid -> u = 0
    }
    float tw = __shfl(tauRow, row);                   // tau_pre (row < 32)
    for (int it = 0; it < WMAXIT; ++it) {
      float s1 = 0.f, s2 = 0.f;
#pragma unroll
      for (int r = 0; r < 4; ++r) {
        float u = fmaxf(xv[r] - tw, 0.f);
        s1 += u; s2 = fmaf(u, u, s2);
      }
#pragma unroll
      for (int off = 1; off < 64; off <<= 1) {
        s1 += __shfl_xor(s1, off, 64);
        s2 += __shfl_xor(s2, off, 64);
      }
      float step = (s2 - 1.0f) / (2.0f * s1);         // s1 >= 1 below root
      tw += step;
      if (step < 1e-7f) break;                        // lane-uniform
    }
    // p = (x - tau)_+^2 written back (same-wave RAW; in-order + waitcnt).
#pragma unroll
    for (int r = 0; r < 4; ++r) {
      const int i = lane + 64 * r;
      if (i < n) {
        float u = fmaxf(xv[r] - tw, 0.f);
        lval[row][i] = u * u;
      }
    }
    // PV branchless: p = 0 entries contribute 0; unroll-4 gives 4
    // independent LDS-broadcast -> V-load chains (pipelined latency).
    float s = 0.f;
#pragma unroll 4
    for (int i = 0; i < n; ++i) {
      s = fmaf(lval[row][i], vp[(size_t)lidx[row][i] * D_ + lane], s);
    }
    op[row * D_ + lane] = s;
  }
}

extern "C" void kernel_launch(void* const* d_in, const int* in_sizes, int n_in,
                              void* d_out, int out_size, void* d_ws, size_t ws_size,
                              hipStream_t stream) {
  const float* q = (const float*)d_in[0];
  const float* k = (const float*)d_in[1];
  const float* v = (const float*)d_in[2];
  float* out = (float*)d_out;
  dim3 grid(BH_ * (S_ / QT));   // 16 * 64 = 1024 blocks
  const size_t need = (size_t)KELEMS * 2 * sizeof(unsigned short);  // 8.4 MB
  if (d_ws != nullptr && ws_size >= need) {
    unsigned short* khi = (unsigned short*)d_ws;
    unsigned short* klo = khi + KELEMS;
    ksplit_kernel<<<dim3(KELEMS / (256 * 4)), dim3(256), 0, stream>>>(k, khi, klo);
    entmax_attn_kernel<true><<<grid, dim3(BLOCK), 0, stream>>>(q, k, khi, klo, v, out);
  } else {
    entmax_attn_kernel<false><<<grid, dim3(BLOCK), 0, stream>>>(q, k, nullptr, nullptr, v, out);
  }
}